// Round 5
// baseline (89890.509 us; speedup 1.0000x reference)
//
#include <hip/hip_runtime.h>
#include <hip/hip_bf16.h>
#include <stdint.h>

using bfrag_t = __attribute__((ext_vector_type(8))) short;  // 8 bf16
using f32x4   = __attribute__((ext_vector_type(4))) float;  // MFMA acc

#define HID  512
#define H3   256
#define NTH  512
#define KSC  2.885390081777927f   // 2*log2(e): tanh(x) = 1 - 2/(exp2(KSC*x)+1)

static __device__ __forceinline__ uint32_t bf16_rne(float f) {
    uint32_t u = __float_as_uint(f);
    return (u + 0x7fffu + ((u >> 16) & 1u)) >> 16;
}
static __device__ __forceinline__ uint32_t pk_bf16(float a, float b) {
    union { __hip_bfloat162 h; uint32_t u; } c;
    c.h = __float22bfloat162_rn(make_float2(a, b));
    return c.u;
}
static __device__ __forceinline__ float fast_exp2(float x) {
#if __has_builtin(__builtin_amdgcn_exp2f)
    return __builtin_amdgcn_exp2f(x);
#else
    return exp2f(x);
#endif
}
static __device__ __forceinline__ float fast_rcp(float x) {
#if __has_builtin(__builtin_amdgcn_rcpf)
    return __builtin_amdgcn_rcpf(x);
#else
    return 1.0f / x;
#endif
}
// input PRE-SCALED by KSC
static __device__ __forceinline__ float ftanh_s(float xs) {
    float e = fast_exp2(xs);
    return 1.0f - 2.0f * fast_rcp(e + 1.0f);
}
static __device__ __forceinline__ bfrag_t frag_of(uint4 v) {
    union { uint4 u; bfrag_t f; } c; c.u = v; return c.f;
}

// ---- prep (same as R3): W2^T/W3^T scaled, MFMA A-frag order; W1 pack; scaled biases ----
__global__ void prep_weights(const float* __restrict__ W1, const float* __restrict__ b1,
                             const float* __restrict__ W2, const float* __restrict__ b2,
                             const float* __restrict__ W3, const float* __restrict__ b3,
                             uint4* __restrict__ o2, uint4* __restrict__ o3,
                             float* __restrict__ w1p, float* __restrict__ b2s,
                             float* __restrict__ b3s)
{
    int id = blockIdx.x * 256 + threadIdx.x;
    if (id < 32768) {
        int l = id & 63, kt = (id >> 6) & 15, mt = id >> 10;
        int m = mt * 16 + (l & 15), k0 = kt * 32 + (l >> 4) * 8;
        uint32_t p[4];
        #pragma unroll
        for (int jj = 0; jj < 4; ++jj) {
            float v0 = KSC * W2[(k0 + jj * 2    ) * 512 + m];
            float v1 = KSC * W2[(k0 + jj * 2 + 1) * 512 + m];
            p[jj] = bf16_rne(v0) | (bf16_rne(v1) << 16);
        }
        o2[id] = make_uint4(p[0], p[1], p[2], p[3]);
    } else if (id < 49152) {
        int id2 = id - 32768;
        int l = id2 & 63, kt = (id2 >> 6) & 15, mt = id2 >> 10;
        int m = mt * 16 + (l & 15), k0 = kt * 32 + (l >> 4) * 8;
        uint32_t p[4];
        #pragma unroll
        for (int jj = 0; jj < 4; ++jj) {
            float v0 = KSC * W3[(k0 + jj * 2    ) * 256 + m];
            float v1 = KSC * W3[(k0 + jj * 2 + 1) * 256 + m];
            p[jj] = bf16_rne(v0) | (bf16_rne(v1) << 16);
        }
        o3[id2] = make_uint4(p[0], p[1], p[2], p[3]);
    } else if (id < 49152 + 1536) {
        int t = id - 49152;
        int ck = t / 24, j = t % 24;
        int f = ck * 8 + (j & 7);
        float v = (j < 8) ? W1[f] : (j < 16) ? W1[512 + f] : b1[f];
        w1p[t] = KSC * v;
    } else if (id < 49152 + 1536 + 512) {
        int i = id - 49152 - 1536; b2s[i] = KSC * b2[i];
    } else if (id < 49152 + 1536 + 512 + 256) {
        int i = id - 49152 - 1536 - 512; b3s[i] = KSC * b3[i];
    }
}

// ---------------- LDS ----------------
// Per slab hbuf: h[ck*64 + r] = 8 bf16 of features [ck*8..ck*8+7], row r (0..63).
struct SmemT {
    uint4  hA[64 * 64];   // 64 KB
    uint4  hB[64 * 64];   // 64 KB
    float  b2[HID];       // scaled
    float  b3[H3];        // scaled
    float  y [128][2];
    float  z [128][2];
    float  ya[128][2];
};

// ================= M-wave stages (wu = 0..3) =================
// L2m: h2pre^T = W2^T @ h1^T + b2 ; M=512/4 waves -> 8 mt, N=64 -> 4 nt, K=512
static __device__ __forceinline__ void L2m_kt(const uint4* __restrict__ h,
                                              const uint4* __restrict__ w2A,
                                              const float* __restrict__ b2,
                                              f32x4 (&acc)[8][4], int wu, int l)
{
    const int q = l >> 4, rr = l & 15;
    #pragma unroll
    for (int mt = 0; mt < 8; ++mt) {
        int m0 = wu * 128 + mt * 16 + q * 4;
        float4 bi = *(const float4*)&b2[m0];
        #pragma unroll
        for (int nt = 0; nt < 4; ++nt) acc[mt][nt] = (f32x4){bi.x, bi.y, bi.z, bi.w};
    }
    uint4 aC[8], aN[8];
    #pragma unroll
    for (int mt = 0; mt < 8; ++mt) aC[mt] = w2A[((wu * 8 + mt) * 16) * 64 + l];
    for (int kt = 0; kt < 16; ++kt) {
        uint4 bF[4];
        #pragma unroll
        for (int nt = 0; nt < 4; ++nt)
            bF[nt] = h[(kt * 4 + q) * 64 + nt * 16 + rr];
        if (kt < 15) {
            #pragma unroll
            for (int mt = 0; mt < 8; ++mt)
                aN[mt] = w2A[((wu * 8 + mt) * 16 + kt + 1) * 64 + l];
        }
        #pragma unroll
        for (int mt = 0; mt < 8; ++mt)
            #pragma unroll
            for (int nt = 0; nt < 4; ++nt)
                acc[mt][nt] = __builtin_amdgcn_mfma_f32_16x16x32_bf16(
                    frag_of(aC[mt]), frag_of(bF[nt]), acc[mt][nt], 0, 0, 0);
        #pragma unroll
        for (int mt = 0; mt < 8; ++mt) aC[mt] = aN[mt];
    }
}
static __device__ __forceinline__ void L2m_wr(uint4* __restrict__ h,
                                              f32x4 (&acc)[8][4], int wu, int l)
{
    const int q = l >> 4, rr = l & 15;
    #pragma unroll
    for (int mt = 0; mt < 8; ++mt) {
        int m0 = wu * 128 + mt * 16 + q * 4;
        int ck = m0 >> 3, hf = (m0 >> 2) & 1;
        #pragma unroll
        for (int nt = 0; nt < 4; ++nt) {
            int n = nt * 16 + rr;
            f32x4 c = acc[mt][nt];
            ((uint2*)h)[((ck * 64 + n) << 1) | hf] =
                make_uint2(pk_bf16(c[0], c[1]), pk_bf16(c[2], c[3]));
        }
    }
}
// L3m: M=256/4 waves -> 4 mt
static __device__ __forceinline__ void L3m_kt(const uint4* __restrict__ h,
                                              const uint4* __restrict__ w3A,
                                              const float* __restrict__ b3,
                                              f32x4 (&acc)[4][4], int wu, int l)
{
    const int q = l >> 4, rr = l & 15;
    #pragma unroll
    for (int mt = 0; mt < 4; ++mt) {
        int m0 = wu * 64 + mt * 16 + q * 4;
        float4 bi = *(const float4*)&b3[m0];
        #pragma unroll
        for (int nt = 0; nt < 4; ++nt) acc[mt][nt] = (f32x4){bi.x, bi.y, bi.z, bi.w};
    }
    uint4 aC[4], aN[4];
    #pragma unroll
    for (int mt = 0; mt < 4; ++mt) aC[mt] = w3A[((wu * 4 + mt) * 16) * 64 + l];
    for (int kt = 0; kt < 16; ++kt) {
        uint4 bF[4];
        #pragma unroll
        for (int nt = 0; nt < 4; ++nt)
            bF[nt] = h[(kt * 4 + q) * 64 + nt * 16 + rr];
        if (kt < 15) {
            #pragma unroll
            for (int mt = 0; mt < 4; ++mt)
                aN[mt] = w3A[((wu * 4 + mt) * 16 + kt + 1) * 64 + l];
        }
        #pragma unroll
        for (int mt = 0; mt < 4; ++mt)
            #pragma unroll
            for (int nt = 0; nt < 4; ++nt)
                acc[mt][nt] = __builtin_amdgcn_mfma_f32_16x16x32_bf16(
                    frag_of(aC[mt]), frag_of(bF[nt]), acc[mt][nt], 0, 0, 0);
        #pragma unroll
        for (int mt = 0; mt < 4; ++mt) aC[mt] = aN[mt];
    }
}
static __device__ __forceinline__ void L3m_wr(uint4* __restrict__ h,
                                              f32x4 (&acc)[4][4], int wu, int l)
{
    const int q = l >> 4, rr = l & 15;
    #pragma unroll
    for (int mt = 0; mt < 4; ++mt) {
        int m0 = wu * 64 + mt * 16 + q * 4;        // 0..255 -> ck 0..31
        int ck = m0 >> 3, hf = (m0 >> 2) & 1;
        #pragma unroll
        for (int nt = 0; nt < 4; ++nt) {
            int n = nt * 16 + rr;
            f32x4 c = acc[mt][nt];
            ((uint2*)h)[((ck * 64 + n) << 1) | hf] =
                make_uint2(pk_bf16(c[0], c[1]), pk_bf16(c[2], c[3]));
        }
    }
}

// ================= V-wave stages (wv = 0..3) =================
// L1: h1 = tanh(z @ W1 + b1) -> bf16 chunks. Wave wv: chunks wv*16..wv*16+15; lane = row.
static __device__ __forceinline__ void V_L1(uint4* __restrict__ h,
                                            const float* __restrict__ zS,
                                            const float* __restrict__ w1v,
                                            int wv, int l)
{
    float z0 = zS[2 * l], z1 = zS[2 * l + 1];
    #pragma unroll
    for (int i = 0; i < 16; ++i) {
        const float* P = w1v + i * 24;   // uniform -> s_load
        int ck = wv * 16 + i;
        float x[8];
        #pragma unroll
        for (int jj = 0; jj < 8; ++jj)
            x[jj] = ftanh_s(fmaf(z0, P[jj], fmaf(z1, P[8 + jj], P[16 + jj])));
        h[ck * 64 + l] = make_uint4(pk_bf16(x[0], x[1]), pk_bf16(x[2], x[3]),
                                    pk_bf16(x[4], x[5]), pk_bf16(x[6], x[7]));
    }
}
// L2e: in-place tanh on 8 chunks starting at cb (pre-act scaled bf16 -> act bf16)
static __device__ __forceinline__ void V_L2e(uint4* __restrict__ h, int cb, int l)
{
    #pragma unroll
    for (int i = 0; i < 8; ++i) {
        int idx = (cb + i) * 64 + l;
        uint4 v = h[idx];
        uint32_t* pu = (uint32_t*)&v;
        uint32_t o[4];
        #pragma unroll
        for (int jj = 0; jj < 4; ++jj) {
            uint32_t uu = pu[jj];
            float t0 = ftanh_s(__uint_as_float(uu << 16));
            float t1 = ftanh_s(__uint_as_float(uu & 0xffff0000u));
            o[jj] = pk_bf16(t0, t1);
        }
        h[idx] = make_uint4(o[0], o[1], o[2], o[3]);
    }
}
// L4 fused: k = tanh(h3pre) @ W4 + b4, then RK4 combine. Wave wv: rows wv*16..+15.
static __device__ __forceinline__ void V_L4fin(const uint4* __restrict__ h,
                                               float* __restrict__ yS, float* __restrict__ zS,
                                               float* __restrict__ yaS,
                                               const float* __restrict__ tp,
                                               const float* __restrict__ b4g,
                                               const float* __restrict__ W4g,
                                               float* __restrict__ out,
                                               int g, int Bn, int growbase, int wv, int l)
{
    const int rloc = l & 15, qq = l >> 4;
    const int row = wv * 16 + rloc;
    float a0 = 0.f, a1 = 0.f;
    #pragma unroll
    for (int j = 0; j < 8; ++j) {
        int ck = qq * 8 + j;
        uint4 hv = h[ck * 64 + row];
        const uint32_t* pu = (const uint32_t*)&hv;
        #pragma unroll
        for (int jj = 0; jj < 4; ++jj) {
            uint32_t uu = pu[jj];
            float h0 = ftanh_s(__uint_as_float(uu << 16));
            float h1 = ftanh_s(__uint_as_float(uu & 0xffff0000u));
            int f = ck * 8 + jj * 2;
            float4 w4 = *(const float4*)&W4g[f * 2];  // W4[f][0..1], W4[f+1][0..1]
            a0 = fmaf(h0, w4.x, fmaf(h1, w4.z, a0));
            a1 = fmaf(h0, w4.y, fmaf(h1, w4.w, a1));
        }
    }
    a0 += __shfl_xor(a0, 16); a0 += __shfl_xor(a0, 32);
    a1 += __shfl_xor(a1, 16); a1 += __shfl_xor(a1, 32);
    if (l < 16) {
        int st = g >> 2, e = g & 3;
        float dt = tp[st + 1] - tp[st];
        float k0 = a0 + b4g[0], k1 = a1 + b4g[1];
        float wg = (e == 0 || e == 3) ? dt * (1.f / 6.f) : dt * (1.f / 3.f);
        float ya0 = yaS[2 * row] + wg * k0, ya1 = yaS[2 * row + 1] + wg * k1;
        yaS[2 * row] = ya0; yaS[2 * row + 1] = ya1;
        if (e < 3) {
            float aa = (e == 2) ? dt : dt * 0.5f;
            zS[2 * row] = yS[2 * row] + aa * k0;
            zS[2 * row + 1] = yS[2 * row + 1] + aa * k1;
        } else {
            yS[2 * row] = ya0; yS[2 * row + 1] = ya1;
            zS[2 * row] = ya0; zS[2 * row + 1] = ya1;
            ((float2*)out)[(size_t)(st + 1) * Bn + growbase + row] = make_float2(ya0, ya1);
        }
    }
}

__global__ __launch_bounds__(NTH, 2) void node_kernel(
    const float* __restrict__ y0, const float* __restrict__ tp,
    const float* __restrict__ W4g, const float* __restrict__ b4g,
    const uint4* __restrict__ w2A, const uint4* __restrict__ w3A,
    const float* __restrict__ w1p, const float* __restrict__ b2s,
    const float* __restrict__ b3s,
    float* __restrict__ out, int Bn, int T)
{
    __shared__ SmemT s;
    const int tid = threadIdx.x;
    const int l   = tid & 63;
    const int w   = tid >> 6;
    const bool isM = (w < 4);                 // waves 0-3: MFMA producers (one per SIMD)
    const int wu  = __builtin_amdgcn_readfirstlane(isM ? w : (w - 4));  // 0..3
    const int b0  = blockIdx.x * 128;

    for (int i = tid; i < HID; i += NTH) s.b2[i] = b2s[i];
    for (int i = tid; i < H3;  i += NTH) s.b3[i] = b3s[i];
    if (tid < 128) {
        float2 v = ((const float2*)y0)[b0 + tid];
        s.y[tid][0] = v.x; s.y[tid][1] = v.y;
        s.z[tid][0] = v.x; s.z[tid][1] = v.y;
        s.ya[tid][0] = v.x; s.ya[tid][1] = v.y;
        ((float2*)out)[b0 + tid] = v;
    }
    __syncthreads();

    const float* w1v = w1p + wu * 384;       // V: 16 chunks x 24 floats
    float* yA = &s.y[0][0];   float* yB = &s.y[64][0];
    float* zA = &s.z[0][0];   float* zB = &s.z[64][0];
    float* aA = &s.ya[0][0];  float* aB = &s.ya[64][0];
    const int E = (T - 1) * 4;

    // Tick schedule (8 barriers/iter); B skewed half-eval behind A:
    // T1 B.L3m | A.L4fin   T2 B.L3wr | A.L1    T3 A.L2m | B.L4fin   T4 A.L2wr | B.L1
    // T5 B.L2m | A.L2e-a   T6 B.L2wr | A.L2e-b T7 A.L3m | B.L2e-a   T8 A.L3wr | B.L2e-b
    for (int i = 0; i <= E; ++i) {
        const bool run = (i < E), lag = (i > 0);
        // T1
        {
            f32x4 c3[4][4];
            if (isM) { if (lag) L3m_kt(s.hB, w3A, s.b3, c3, wu, l); }
            else     { if (lag) V_L4fin(s.hA, yA, zA, aA, tp, b4g, W4g, out, i - 1, Bn, b0, wu, l); }
            __syncthreads();
            // T2
            if (isM) { if (lag) L3m_wr(s.hB, c3, wu, l); }
            else     { if (run) V_L1(s.hA, zA, w1v, wu, l); }
            __syncthreads();
        }
        // T3
        {
            f32x4 c2[8][4];
            if (isM) { if (run) L2m_kt(s.hA, w2A, s.b2, c2, wu, l); }
            else     { if (lag) V_L4fin(s.hB, yB, zB, aB, tp, b4g, W4g, out, i - 1, Bn, b0 + 64, wu, l); }
            __syncthreads();
            // T4
            if (isM) { if (run) L2m_wr(s.hA, c2, wu, l); }
            else     { if (run) V_L1(s.hB, zB, w1v, wu, l); }
            __syncthreads();
        }
        // T5
        {
            f32x4 c2[8][4];
            if (isM) { if (run) L2m_kt(s.hB, w2A, s.b2, c2, wu, l); }
            else     { if (run) V_L2e(s.hA, wu * 8, l); }
            __syncthreads();
            // T6
            if (isM) { if (run) L2m_wr(s.hB, c2, wu, l); }
            else     { if (run) V_L2e(s.hA, 32 + wu * 8, l); }
            __syncthreads();
        }
        // T7
        {
            f32x4 c3[4][4];
            if (isM) { if (run) L3m_kt(s.hA, w3A, s.b3, c3, wu, l); }
            else     { if (run) V_L2e(s.hB, wu * 8, l); }
            __syncthreads();
            // T8
            if (isM) { if (run) L3m_wr(s.hA, c3, wu, l); }
            else     { if (run) V_L2e(s.hB, 32 + wu * 8, l); }
            __syncthreads();
        }
    }
}

extern "C" void kernel_launch(void* const* d_in, const int* in_sizes, int n_in,
                              void* d_out, int out_size, void* d_ws, size_t ws_size,
                              hipStream_t stream)
{
    const float* y0 = (const float*)d_in[0];
    const float* tp = (const float*)d_in[1];
    const float* W1 = (const float*)d_in[2];
    const float* b1 = (const float*)d_in[3];
    const float* W2 = (const float*)d_in[4];
    const float* b2 = (const float*)d_in[5];
    const float* W3 = (const float*)d_in[6];
    const float* b3 = (const float*)d_in[7];
    const float* W4 = (const float*)d_in[8];
    const float* b4 = (const float*)d_in[9];
    float* out = (float*)d_out;

    const int Bn = in_sizes[0] / 2;
    const int T  = in_sizes[1];

    uint4* w2A = (uint4*)d_ws;            // 512 KB
    uint4* w3A = w2A + 32768;             // 256 KB
    float* w1p = (float*)(w3A + 16384);   // 1536 floats
    float* b2s = w1p + 1536;              // 512
    float* b3s = b2s + 512;               // 256

    prep_weights<<<201, 256, 0, stream>>>(W1, b1, W2, b2, W3, b3,
                                          w2A, w3A, w1p, b2s, b3s);
    node_kernel<<<Bn / 128, NTH, 0, stream>>>(y0, tp, W4, b4,
                                              w2A, w3A, w1p, b2s, b3s, out, Bn, T);
}

// Round 6
// 30016.302 us; speedup vs baseline: 2.9947x; 2.9947x over previous
//
#include <hip/hip_runtime.h>
#include <hip/hip_bf16.h>
#include <stdint.h>

using bfrag_t = __attribute__((ext_vector_type(8))) short;   // 8 bf16 (4 VGPRs)
using f32x16  = __attribute__((ext_vector_type(16))) float;  // 32x32 MFMA acc

#define HID  512
#define H3   256
#define RB   64       // rows per block; 2 blocks/CU (LDS ~74KB)
#define NTH  512      // 8 waves
#define KSC  2.885390081777927f   // 2*log2(e): tanh(x) = 1 - 2/(exp2(KSC*x)+1)

static __device__ __forceinline__ uint32_t bf16_rne(float f) {
    uint32_t u = __float_as_uint(f);
    return (u + 0x7fffu + ((u >> 16) & 1u)) >> 16;
}
static __device__ __forceinline__ uint32_t pk_bf16(float a, float b) {
    union { __hip_bfloat162 h; uint32_t u; } c;
    c.h = __float22bfloat162_rn(make_float2(a, b));   // v_cvt_pk_bf16_f32
    return c.u;
}
static __device__ __forceinline__ float fast_exp2(float x) {
#if __has_builtin(__builtin_amdgcn_exp2f)
    return __builtin_amdgcn_exp2f(x);
#else
    return exp2f(x);
#endif
}
static __device__ __forceinline__ float fast_rcp(float x) {
#if __has_builtin(__builtin_amdgcn_rcpf)
    return __builtin_amdgcn_rcpf(x);
#else
    return 1.0f / x;
#endif
}
// input PRE-SCALED by KSC
static __device__ __forceinline__ float ftanh_s(float xs) {
    float e = fast_exp2(xs);
    return 1.0f - 2.0f * fast_rcp(e + 1.0f);
}
static __device__ __forceinline__ bfrag_t frag_of(uint4 v) {
    union { uint4 u; bfrag_t f; } c; c.u = v; return c.f;
}

// ---------------- prep: swizzle W2^T / W3^T (scaled) into 32x32x16 A-frag order ----
// A-frag (32x32x16): lane l holds A[m = mt*32 + (l&31)][k = kt*16 + (l>>5)*8 + j], j=0..7.
// Slot: o[(mt*32 + kt)*64 + l] = uint4 (8 bf16).
__global__ void prep_weights(const float* __restrict__ W1, const float* __restrict__ b1,
                             const float* __restrict__ W2, const float* __restrict__ b2,
                             const float* __restrict__ W3, const float* __restrict__ b3,
                             uint4* __restrict__ o2, uint4* __restrict__ o3,
                             float* __restrict__ w1p, float* __restrict__ b2s,
                             float* __restrict__ b3s)
{
    int id = blockIdx.x * 256 + threadIdx.x;
    if (id < 32768) {                       // W2: 16 mt * 32 kt * 64 lanes
        int l = id & 63, kt = (id >> 6) & 31, mt = id >> 11;
        int m = mt * 32 + (l & 31), k0 = kt * 16 + (l >> 5) * 8;
        uint32_t p[4];
        #pragma unroll
        for (int jj = 0; jj < 4; ++jj) {
            float v0 = KSC * W2[(k0 + jj * 2    ) * 512 + m];   // W2^T[m][k] = W2[k][m]
            float v1 = KSC * W2[(k0 + jj * 2 + 1) * 512 + m];
            p[jj] = bf16_rne(v0) | (bf16_rne(v1) << 16);
        }
        o2[id] = make_uint4(p[0], p[1], p[2], p[3]);
    } else if (id < 49152) {                // W3: 8 mt * 32 kt * 64 lanes
        int id2 = id - 32768;
        int l = id2 & 63, kt = (id2 >> 6) & 31, mt = id2 >> 11;
        int m = mt * 32 + (l & 31), k0 = kt * 16 + (l >> 5) * 8;
        uint32_t p[4];
        #pragma unroll
        for (int jj = 0; jj < 4; ++jj) {
            float v0 = KSC * W3[(k0 + jj * 2    ) * 256 + m];
            float v1 = KSC * W3[(k0 + jj * 2 + 1) * 256 + m];
            p[jj] = bf16_rne(v0) | (bf16_rne(v1) << 16);
        }
        o3[id2] = make_uint4(p[0], p[1], p[2], p[3]);
    } else if (id < 49152 + 1536) {         // W1 pack: 64 chunks x 24 floats
        int t = id - 49152;
        int ck = t / 24, j = t % 24;
        int f = ck * 8 + (j & 7);
        float v = (j < 8) ? W1[f] : (j < 16) ? W1[512 + f] : b1[f];
        w1p[t] = KSC * v;
    } else if (id < 49152 + 1536 + 512) {
        int i = id - 49152 - 1536; b2s[i] = KSC * b2[i];
    } else if (id < 49152 + 1536 + 512 + 256) {
        int i = id - 49152 - 1536 - 512; b3s[i] = KSC * b3[i];
    }
}

// ---------------- main kernel (R3 phase-serial structure, RB=64, 2 blocks/CU) ----------
// hbuf[ck*64 + r] = 8 bf16 features [ck*8..ck*8+7] of row r. This is both the
// 32x32x16 B-frag source (lane: n = nt*32 + (l&31), ck = kt*2 + (l>>5)) and the
// epilogue target (C/D: 4 groups of 4 contiguous feats per lane -> uint2 writes).
struct SmemT {
    uint4  hbuf[64 * RB];    // 64 KB
    float  b2[HID];          // scaled
    float  b3[H3];           // scaled
    float  y [RB][2];
    float  z [RB][2];
    float  ya[RB][2];
    float  part[8][RB][2];   // layer4 partials
};

__global__ __launch_bounds__(NTH, 4) void node_kernel(
    const float* __restrict__ y0, const float* __restrict__ tp,
    const float* __restrict__ W4g, const float* __restrict__ b4g,
    const uint4* __restrict__ w2A, const uint4* __restrict__ w3A,
    const float* __restrict__ w1p, const float* __restrict__ b2s,
    const float* __restrict__ b3s,
    float* __restrict__ out, int Bn, int T)
{
    __shared__ SmemT s;
    const int tid = threadIdx.x;
    const int l   = tid & 63;
    const int w   = tid >> 6;                              // wave 0..7
    const int wu  = __builtin_amdgcn_readfirstlane(w);
    const int q2  = l >> 5, r32 = l & 31;
    const int b0  = blockIdx.x * RB;

    for (int i = tid; i < HID; i += NTH) s.b2[i] = b2s[i];
    for (int i = tid; i < H3;  i += NTH) s.b3[i] = b3s[i];
    if (tid < RB) {
        float2 v = ((const float2*)y0)[b0 + tid];
        s.y[tid][0] = v.x; s.y[tid][1] = v.y;
        ((float2*)out)[b0 + tid] = v;          // trajectory[0] = y0
    }
    __syncthreads();

    const float* w1w = w1p + wu * 192;         // this wave's 8 chunks (uniform)

    for (int st = 0; st < T - 1; ++st) {
        float dt = tp[st + 1] - tp[st];
        if (tid < RB) {
            s.z [tid][0] = s.y[tid][0]; s.z [tid][1] = s.y[tid][1];
            s.ya[tid][0] = s.y[tid][0]; s.ya[tid][1] = s.y[tid][1];
        }
        __syncthreads();

        for (int e = 0; e < 4; ++e) {
            // ---- layer1: h1 = tanh(z @ W1 + b1); lane = row, wave = 8 chunks ----
            {
                float z0 = s.z[l][0], z1 = s.z[l][1];
                #pragma unroll
                for (int i = 0; i < 8; ++i) {
                    const float* P = w1w + i * 24;   // uniform -> s_load
                    int ck = wu * 8 + i;
                    float x[8];
                    #pragma unroll
                    for (int jj = 0; jj < 8; ++jj)
                        x[jj] = ftanh_s(fmaf(z0, P[jj], fmaf(z1, P[8 + jj], P[16 + jj])));
                    s.hbuf[ck * RB + l] = make_uint4(
                        pk_bf16(x[0], x[1]), pk_bf16(x[2], x[3]),
                        pk_bf16(x[4], x[5]), pk_bf16(x[6], x[7]));
                }
            }
            __syncthreads();

            // ---- layer2: h2^T = W2^T @ h1^T + b2  (M=512, N=64, K=512, 32x32x16) ----
            {
                f32x16 acc[2][2];
                #pragma unroll
                for (int mt = 0; mt < 2; ++mt) {
                    int mbase = (wu * 2 + mt) * 32;
                    #pragma unroll
                    for (int r2 = 0; r2 < 4; ++r2) {
                        float4 bi = *(const float4*)&s.b2[mbase + 8 * r2 + 4 * q2];
                        #pragma unroll
                        for (int nt = 0; nt < 2; ++nt) {
                            acc[mt][nt][4 * r2 + 0] = bi.x;
                            acc[mt][nt][4 * r2 + 1] = bi.y;
                            acc[mt][nt][4 * r2 + 2] = bi.z;
                            acc[mt][nt][4 * r2 + 3] = bi.w;
                        }
                    }
                }
                uint4 aC[2], aN[2];
                aC[0] = w2A[((wu * 2 + 0) * 32) * 64 + l];
                aC[1] = w2A[((wu * 2 + 1) * 32) * 64 + l];
                for (int kt = 0; kt < 32; ++kt) {
                    uint4 bF0 = s.hbuf[(kt * 2 + q2) * RB + r32];
                    uint4 bF1 = s.hbuf[(kt * 2 + q2) * RB + 32 + r32];
                    if (kt < 31) {
                        aN[0] = w2A[((wu * 2 + 0) * 32 + kt + 1) * 64 + l];
                        aN[1] = w2A[((wu * 2 + 1) * 32 + kt + 1) * 64 + l];
                    }
                    acc[0][0] = __builtin_amdgcn_mfma_f32_32x32x16_bf16(
                        frag_of(aC[0]), frag_of(bF0), acc[0][0], 0, 0, 0);
                    acc[0][1] = __builtin_amdgcn_mfma_f32_32x32x16_bf16(
                        frag_of(aC[0]), frag_of(bF1), acc[0][1], 0, 0, 0);
                    acc[1][0] = __builtin_amdgcn_mfma_f32_32x32x16_bf16(
                        frag_of(aC[1]), frag_of(bF0), acc[1][0], 0, 0, 0);
                    acc[1][1] = __builtin_amdgcn_mfma_f32_32x32x16_bf16(
                        frag_of(aC[1]), frag_of(bF1), acc[1][1], 0, 0, 0);
                    aC[0] = aN[0]; aC[1] = aN[1];
                }
                __syncthreads();   // all waves done reading h1
                // epilogue: tanh, pack, overwrite hbuf with h2
                #pragma unroll
                for (int mt = 0; mt < 2; ++mt) {
                    int cb = (wu * 2 + mt) * 4;          // mbase >> 3
                    #pragma unroll
                    for (int nt = 0; nt < 2; ++nt) {
                        int n = nt * 32 + r32;
                        #pragma unroll
                        for (int r2 = 0; r2 < 4; ++r2) {
                            float t0 = ftanh_s(acc[mt][nt][4 * r2 + 0]);
                            float t1 = ftanh_s(acc[mt][nt][4 * r2 + 1]);
                            float t2 = ftanh_s(acc[mt][nt][4 * r2 + 2]);
                            float t3 = ftanh_s(acc[mt][nt][4 * r2 + 3]);
                            ((uint2*)s.hbuf)[(((cb + r2) * RB + n) << 1) | q2] =
                                make_uint2(pk_bf16(t0, t1), pk_bf16(t2, t3));
                        }
                    }
                }
                __syncthreads();
            }

            // ---- layer3: h3^T = W3^T @ h2^T + b3  (M=256, N=64, K=512, 32x32x16) ----
            {
                f32x16 acc[2];
                {
                    int mbase = wu * 32;
                    #pragma unroll
                    for (int r2 = 0; r2 < 4; ++r2) {
                        float4 bi = *(const float4*)&s.b3[mbase + 8 * r2 + 4 * q2];
                        #pragma unroll
                        for (int nt = 0; nt < 2; ++nt) {
                            acc[nt][4 * r2 + 0] = bi.x;
                            acc[nt][4 * r2 + 1] = bi.y;
                            acc[nt][4 * r2 + 2] = bi.z;
                            acc[nt][4 * r2 + 3] = bi.w;
                        }
                    }
                }
                uint4 aC = w3A[(wu * 32) * 64 + l], aN;
                for (int kt = 0; kt < 32; ++kt) {
                    uint4 bF0 = s.hbuf[(kt * 2 + q2) * RB + r32];
                    uint4 bF1 = s.hbuf[(kt * 2 + q2) * RB + 32 + r32];
                    if (kt < 31) aN = w3A[(wu * 32 + kt + 1) * 64 + l];
                    acc[0] = __builtin_amdgcn_mfma_f32_32x32x16_bf16(
                        frag_of(aC), frag_of(bF0), acc[0], 0, 0, 0);
                    acc[1] = __builtin_amdgcn_mfma_f32_32x32x16_bf16(
                        frag_of(aC), frag_of(bF1), acc[1], 0, 0, 0);
                    aC = aN;
                }
                __syncthreads();   // all waves done reading h2
                {
                    int cb = wu * 4;                     // chunks 0..31
                    #pragma unroll
                    for (int nt = 0; nt < 2; ++nt) {
                        int n = nt * 32 + r32;
                        #pragma unroll
                        for (int r2 = 0; r2 < 4; ++r2) {
                            float t0 = ftanh_s(acc[nt][4 * r2 + 0]);
                            float t1 = ftanh_s(acc[nt][4 * r2 + 1]);
                            float t2 = ftanh_s(acc[nt][4 * r2 + 2]);
                            float t3 = ftanh_s(acc[nt][4 * r2 + 3]);
                            ((uint2*)s.hbuf)[(((cb + r2) * RB + n) << 1) | q2] =
                                make_uint2(pk_bf16(t0, t1), pk_bf16(t2, t3));
                        }
                    }
                }
                __syncthreads();
            }

            // ---- layer4 partials: contiguous-row reads, uniform W4 loads ----
            {
                int r  = tid & 63;
                int qq = __builtin_amdgcn_readfirstlane(tid >> 6);   // 0..7
                float a0 = 0.f, a1 = 0.f;
                #pragma unroll
                for (int j = 0; j < 4; ++j) {
                    int ck = qq * 4 + j;
                    uint4 hv = s.hbuf[ck * RB + r];
                    const uint32_t* pu = (const uint32_t*)&hv;
                    #pragma unroll
                    for (int jj = 0; jj < 4; ++jj) {
                        uint32_t uu = pu[jj];
                        float h0 = __uint_as_float(uu << 16);
                        float h1 = __uint_as_float(uu & 0xffff0000u);
                        int f = ck * 8 + jj * 2;                     // uniform
                        float4 w4 = *(const float4*)&W4g[f * 2];
                        a0 = fmaf(h0, w4.x, fmaf(h1, w4.z, a0));
                        a1 = fmaf(h0, w4.y, fmaf(h1, w4.w, a1));
                    }
                }
                s.part[qq][r][0] = a0; s.part[qq][r][1] = a1;
            }
            __syncthreads();

            // ---- reduce partials + RK4 combine ----
            if (tid < RB) {
                float k0 = b4g[0], k1 = b4g[1];
                #pragma unroll
                for (int qq = 0; qq < 8; ++qq) {
                    k0 += s.part[qq][tid][0];
                    k1 += s.part[qq][tid][1];
                }
                float wg = (e == 0 || e == 3) ? dt * (1.f / 6.f) : dt * (1.f / 3.f);
                s.ya[tid][0] += wg * k0; s.ya[tid][1] += wg * k1;
                if (e < 3) {
                    float aa = (e == 2) ? dt : dt * 0.5f;
                    s.z[tid][0] = s.y[tid][0] + aa * k0;
                    s.z[tid][1] = s.y[tid][1] + aa * k1;
                } else {
                    s.y[tid][0] = s.ya[tid][0]; s.y[tid][1] = s.ya[tid][1];
                    ((float2*)out)[(size_t)(st + 1) * Bn + b0 + tid] =
                        make_float2(s.ya[tid][0], s.ya[tid][1]);
                }
            }
            __syncthreads();
        }
    }
}

extern "C" void kernel_launch(void* const* d_in, const int* in_sizes, int n_in,
                              void* d_out, int out_size, void* d_ws, size_t ws_size,
                              hipStream_t stream)
{
    const float* y0 = (const float*)d_in[0];
    const float* tp = (const float*)d_in[1];
    const float* W1 = (const float*)d_in[2];
    const float* b1 = (const float*)d_in[3];
    const float* W2 = (const float*)d_in[4];
    const float* b2 = (const float*)d_in[5];
    const float* W3 = (const float*)d_in[6];
    const float* b3 = (const float*)d_in[7];
    const float* W4 = (const float*)d_in[8];
    const float* b4 = (const float*)d_in[9];
    float* out = (float*)d_out;

    const int Bn = in_sizes[0] / 2;
    const int T  = in_sizes[1];

    uint4* w2A = (uint4*)d_ws;            // 32768 uint4 = 512 KB
    uint4* w3A = w2A + 32768;             // 16384 uint4 = 256 KB
    float* w1p = (float*)(w3A + 16384);   // 1536 floats (scaled W1 pack)
    float* b2s = w1p + 1536;              // 512 floats
    float* b3s = b2s + 512;               // 256 floats

    prep_weights<<<201, 256, 0, stream>>>(W1, b1, W2, b2, W3, b3,
                                          w2A, w3A, w1p, b2s, b3s);
    node_kernel<<<Bn / RB, NTH, 0, stream>>>(y0, tp, W4, b4,
                                             w2A, w3A, w1p, b2s, b3s, out, Bn, T);
}